// Round 1
// baseline (602.964 us; speedup 1.0000x reference)
//
#include <hip/hip_runtime.h>

constexpr int SEQ = 2048;
constexpr int HD  = 64;   // head dim
constexpr int NH  = 8;    // heads
constexpr int NB  = 8;    // batch
constexpr int BM  = 64;   // query rows per block (4 waves x 16)
constexpr int BN  = 64;   // key/value columns per iteration
constexpr int KST = 72;   // LDS row stride in bf16 elems (64 + 8 pad, 16B-aligned)
constexpr float INV_T = 0.125f;

typedef __attribute__((ext_vector_type(8))) short bf16x8;
typedef __attribute__((ext_vector_type(4))) short s16x4;
typedef __attribute__((ext_vector_type(4))) float f32x4;

__device__ __forceinline__ short f2bf(float f) {
  unsigned u = __builtin_bit_cast(unsigned, f);
  u += 0x7fffu + ((u >> 16) & 1u);   // RNE
  return (short)(u >> 16);
}
__device__ __forceinline__ float bf2f(short s) {
  unsigned u = ((unsigned)(unsigned short)s) << 16;
  return __builtin_bit_cast(float, u);
}

__global__ __launch_bounds__(256, 2)
void attn_fused(const float* __restrict__ q, const float* __restrict__ kk,
                const float* __restrict__ vv, const float* __restrict__ pos,
                const float* __restrict__ mask, float* __restrict__ out)
{
  __shared__ short lds_k[BN * KST];        // K[j][d]  bf16
  __shared__ short lds_v[HD * KST];        // V^T[d][j] bf16
  __shared__ short lds_p[4][16 * KST];     // per-wave P[i_local][j] bf16

  const int bh   = blockIdx.y;             // b*NH + h
  const int h    = bh & (NH - 1);
  const int i0   = blockIdx.x * BM;
  const int tid  = threadIdx.x;
  const int wave = tid >> 6;
  const int lane = tid & 63;
  const int quad = lane >> 4;
  const int lq   = lane & 15;

  // ---- Q A-fragments (scaled by INV_T, exact pow2) ----
  bf16x8 aq[2];
  {
    const float* qp = q + ((size_t)bh * SEQ + i0 + wave * 16 + lq) * HD + quad * 8;
    for (int k0 = 0; k0 < 2; ++k0) {
      f32x4 x = *(const f32x4*)(qp + k0 * 32);
      f32x4 y = *(const f32x4*)(qp + k0 * 32 + 4);
      for (int j = 0; j < 4; ++j) {
        aq[k0][j]     = f2bf(x[j] * INV_T);
        aq[k0][4 + j] = f2bf(y[j] * INV_T);
      }
    }
  }

  f32x4 oacc[4];
  for (int d = 0; d < 4; ++d) oacc[d] = (f32x4){0.f, 0.f, 0.f, 0.f};
  float mrun[4] = {-INFINITY, -INFINITY, -INFINITY, -INFINITY};
  float lrun[4] = {0.f, 0.f, 0.f, 0.f};

  const size_t kvbase = (size_t)bh * SEQ * HD;

  for (int jt = 0; jt < SEQ / BN; ++jt) {
    const int j0 = jt * BN;
    __syncthreads();   // protect LDS K/V from previous iteration's readers

    // ---- stage K (rows) and V (transposed) into LDS as bf16 ----
    for (int e = 0; e < 4; ++e) {
      int idx = e * 256 + tid;          // 0..1023 float4-slots of the 64x64 tile
      int j   = idx >> 4;
      int d4  = (idx & 15) << 2;
      f32x4 kf = *(const f32x4*)(kk + kvbase + (size_t)(j0 + j) * HD + d4);
      s16x4 ks;
      for (int c = 0; c < 4; ++c) ks[c] = f2bf(kf[c]);
      *(s16x4*)&lds_k[j * KST + d4] = ks;
      f32x4 vf = *(const f32x4*)(vv + kvbase + (size_t)(j0 + j) * HD + d4);
      for (int c = 0; c < 4; ++c) lds_v[(d4 + c) * KST + j] = f2bf(vf[c]);
    }
    __syncthreads();

    // ---- mask / pos for this lane's 16 (row,col) score elements ----
    float mk[4][4], pz[4][4];          // [reg r][sub-tile]
    for (int r = 0; r < 4; ++r) {
      const int i = i0 + wave * 16 + quad * 4 + r;
      const float* mrow = mask + (size_t)i * SEQ + j0 + lq;
      const float* prow = pos + ((size_t)h * SEQ + i) * SEQ + j0 + lq;
      for (int sub = 0; sub < 4; ++sub) {
        mk[r][sub] = mrow[sub * 16];
        pz[r][sub] = prow[sub * 16];
      }
    }

    // ---- S = (Q*invT) K^T via MFMA ----
    f32x4 sa[4];
    for (int sub = 0; sub < 4; ++sub) sa[sub] = (f32x4){0.f, 0.f, 0.f, 0.f};
    for (int k0 = 0; k0 < 2; ++k0)
      for (int sub = 0; sub < 4; ++sub) {
        bf16x8 bk = *(const bf16x8*)&lds_k[(sub * 16 + lq) * KST + k0 * 32 + quad * 8];
        sa[sub] = __builtin_amdgcn_mfma_f32_16x16x32_bf16(aq[k0], bk, sa[sub], 0, 0, 0);
      }

    // ---- online softmax; row (quad*4+r) lives in this quad's 16 lanes ----
    for (int r = 0; r < 4; ++r) {
      float s0 = mk[r][0] * (sa[0][r] + pz[r][0]);
      float s1 = mk[r][1] * (sa[1][r] + pz[r][1]);
      float s2 = mk[r][2] * (sa[2][r] + pz[r][2]);
      float s3 = mk[r][3] * (sa[3][r] + pz[r][3]);
      float rm = fmaxf(fmaxf(s0, s1), fmaxf(s2, s3));
      for (int off = 1; off < 16; off <<= 1)
        rm = fmaxf(rm, __shfl_xor(rm, off));
      float mn = fmaxf(mrun[r], rm);
      float al = __expf(mrun[r] - mn);   // 0 on first tile (-inf - finite)
      mrun[r] = mn;
      short p0 = f2bf(__expf(s0 - mn));
      short p1 = f2bf(__expf(s1 - mn));
      short p2 = f2bf(__expf(s2 - mn));
      short p3 = f2bf(__expf(s3 - mn));
      // denominator from the *rounded* p so num/den rounding cancels
      float ps = bf2f(p0) + bf2f(p1) + bf2f(p2) + bf2f(p3);
      for (int off = 1; off < 16; off <<= 1)
        ps += __shfl_xor(ps, off);
      lrun[r] = lrun[r] * al + ps;
      for (int d = 0; d < 4; ++d) oacc[d][r] *= al;
      short* pr = &lds_p[wave][(quad * 4 + r) * KST + lq];
      pr[0] = p0; pr[16] = p1; pr[32] = p2; pr[48] = p3;
    }
    // P writes/reads are wave-private: completion fence only, no block barrier
    asm volatile("s_waitcnt lgkmcnt(0)" ::: "memory");

    // ---- O += P V ----
    for (int k0 = 0; k0 < 2; ++k0) {
      bf16x8 ap = *(const bf16x8*)&lds_p[wave][lq * KST + k0 * 32 + quad * 8];
      for (int d = 0; d < 4; ++d) {
        bf16x8 bv = *(const bf16x8*)&lds_v[(d * 16 + lq) * KST + k0 * 32 + quad * 8];
        oacc[d] = __builtin_amdgcn_mfma_f32_16x16x32_bf16(ap, bv, oacc[d], 0, 0, 0);
      }
    }
  }

  // ---- epilogue: normalize and store ----
  for (int r = 0; r < 4; ++r) {
    const int i = i0 + wave * 16 + quad * 4 + r;
    const float inv = 1.0f / lrun[r];
    float* orow = out + ((size_t)bh * SEQ + i) * HD + lq;
    for (int d = 0; d < 4; ++d) orow[d * 16] = oacc[d][r] * inv;
  }
}

extern "C" void kernel_launch(void* const* d_in, const int* in_sizes, int n_in,
                              void* d_out, int out_size, void* d_ws, size_t ws_size,
                              hipStream_t stream) {
  const float* q    = (const float*)d_in[0];
  const float* k    = (const float*)d_in[1];
  const float* v    = (const float*)d_in[2];
  const float* pos  = (const float*)d_in[3];
  const float* mask = (const float*)d_in[4];
  float* out = (float*)d_out;
  dim3 grid(SEQ / BM, NB * NH);
  attn_fused<<<grid, dim3(256), 0, stream>>>(q, k, v, pos, mask, out);
}

// Round 2
// 498.132 us; speedup vs baseline: 1.2104x; 1.2104x over previous
//
#include <hip/hip_runtime.h>

constexpr int SEQ = 2048;
constexpr int HD  = 64;
constexpr int NH  = 8;
constexpr int NB  = 8;
constexpr int BM  = 64;
constexpr int BN  = 64;
constexpr int KST = 72;   // LDS row stride (shorts): 144 B = 9*16 -> b128-aligned, conflict-free
constexpr float INV_T = 0.125f;
constexpr float LOG2E = 1.4426950408889634f;

typedef __attribute__((ext_vector_type(8))) short bf16x8;
typedef __attribute__((ext_vector_type(8))) short s16x8;
typedef __attribute__((ext_vector_type(4))) short s16x4;
typedef __attribute__((ext_vector_type(4))) float f32x4;
typedef __attribute__((ext_vector_type(4))) unsigned u32x4;

__device__ __forceinline__ short f2bf(float f) {
  unsigned u = __builtin_bit_cast(unsigned, f);
  u += 0x7fffu + ((u >> 16) & 1u);   // RNE
  return (short)(u >> 16);
}
__device__ __forceinline__ float bf2f(short s) {
  unsigned u = ((unsigned)(unsigned short)s) << 16;
  return __builtin_bit_cast(float, u);
}
__device__ __forceinline__ float fast_exp2(float x) {
#if __has_builtin(__builtin_amdgcn_exp2f)
  return __builtin_amdgcn_exp2f(x);
#else
  return exp2f(x);
#endif
}

// ---------------- prep 1: K -> bf16 rows, V -> bf16 transposed [bh][d][j] ----------------
__global__ __launch_bounds__(256)
void prep_kv(const float* __restrict__ k, const float* __restrict__ v,
             unsigned short* __restrict__ kb, unsigned short* __restrict__ vt)
{
  __shared__ unsigned short t[HD * KST];
  const int bh = blockIdx.y, jt = blockIdx.x, tid = threadIdx.x;
  const size_t base = (size_t)bh * SEQ * HD + (size_t)jt * BN * HD;  // tile origin (elems)

  // K: tile is 4096 contiguous elems; thread converts 16 at 16*tid
  {
    const float* kp = k + base + 16 * tid;
    unsigned short ko[16];
    for (int e = 0; e < 4; ++e) {
      f32x4 x = *(const f32x4*)(kp + 4 * e);
      for (int c = 0; c < 4; ++c) ko[4 * e + c] = (unsigned short)f2bf(x[c]);
    }
    *(s16x8*)(kb + base + 16 * tid)     = *(const s16x8*)&ko[0];
    *(s16x8*)(kb + base + 16 * tid + 8) = *(const s16x8*)&ko[8];
  }
  // V: read rows coalesced, transpose via LDS (conflicts ok here; tiny kernel)
  {
    const float* vp = v + base + 16 * tid;
    const int j = tid >> 2, d0 = (tid & 3) * 16;
    for (int e = 0; e < 4; ++e) {
      f32x4 x = *(const f32x4*)(vp + 4 * e);
      for (int c = 0; c < 4; ++c) t[(d0 + 4 * e + c) * KST + j] = (unsigned short)f2bf(x[c]);
    }
  }
  __syncthreads();
  {
    const int d = tid >> 2, ch = tid & 3;
    const size_t ob = (size_t)bh * HD * SEQ + (size_t)d * SEQ + jt * BN + ch * 16;
    *(s16x8*)(vt + ob)     = *(const s16x8*)&t[d * KST + ch * 16];
    *(s16x8*)(vt + ob + 8) = *(const s16x8*)&t[d * KST + ch * 16 + 8];
  }
}

// ---------------- prep 2: pack (mask*log2e | mask*pos*log2e) bf16 pair, C-layout order ----------------
// dword index D = (((h*32 + jt)*2048 + i)*16 + lq)*4 + sub ;  j = jt*64 + sub*16 + lq
__global__ __launch_bounds__(256)
void prep_pack(const float* __restrict__ pos, const float* __restrict__ mask,
               unsigned* __restrict__ pk)
{
  const int w  = blockIdx.x * 256 + threadIdx.x;   // 0 .. 8388607, covers 4 dwords
  const int lq = w & 15;
  const int i  = (w >> 4) & 2047;
  const int jh = w >> 15;
  const int jt = jh & 31, h = jh >> 5;
  u32x4 o;
  for (int sub = 0; sub < 4; ++sub) {
    const int j = jt * 64 + sub * 16 + lq;
    float m = mask[(size_t)i * SEQ + j];
    float p = pos[((size_t)h * SEQ + i) * SEQ + j];
    unsigned mb = (unsigned)(unsigned short)f2bf(m * LOG2E);
    unsigned pb = (unsigned)(unsigned short)f2bf(m * p * LOG2E);
    o[sub] = (mb << 16) | pb;
  }
  *(u32x4*)(pk + (size_t)4 * w) = o;
}

// ---------------- main fused attention ----------------
__global__ __launch_bounds__(256, 8)
void attn_main(const float* __restrict__ q, const unsigned short* __restrict__ kb,
               const unsigned short* __restrict__ vt, const unsigned* __restrict__ pk,
               float* __restrict__ out)
{
  __shared__ unsigned short lds_k[BN * KST];   // K tile; ALIASED as P after barrier-3
  __shared__ unsigned short lds_v[HD * KST];   // V^T tile

  const int bh = blockIdx.y, h = bh & (NH - 1);
  const int i0 = blockIdx.x * BM;
  const int tid = threadIdx.x, wave = tid >> 6, lane = tid & 63;
  const int quad = lane >> 4, lq = lane & 15;

  // Q A-frags (scaled by 1/8 before rounding: exact exponent shift)
  bf16x8 aq[2];
  {
    const float* qp = q + ((size_t)bh * SEQ + i0 + wave * 16 + lq) * HD + quad * 8;
    for (int k0 = 0; k0 < 2; ++k0) {
      f32x4 x = *(const f32x4*)(qp + k0 * 32);
      f32x4 y = *(const f32x4*)(qp + k0 * 32 + 4);
      for (int c = 0; c < 4; ++c) {
        aq[k0][c]     = f2bf(x[c] * INV_T);
        aq[k0][4 + c] = f2bf(y[c] * INV_T);
      }
    }
  }

  f32x4 oacc[4];
  for (int d = 0; d < 4; ++d) oacc[d] = (f32x4){0.f, 0.f, 0.f, 0.f};
  float lrun[4] = {0.f, 0.f, 0.f, 0.f};

  // staging addresses: thread covers 16 shorts of each 64x64 bf16 tile (2 x b128)
  const int lw = (tid >> 3) * KST + (tid & 7) * 8;          // LDS dst (shorts), e-stride 32*KST
  const unsigned short* kgb = kb + (size_t)bh * SEQ * HD + 8 * tid;                      // + jt*4096, e*2048
  const unsigned short* vgb = vt + (size_t)bh * HD * SEQ + (tid >> 3) * SEQ + (tid & 7) * 8; // + jt*64, e*32*SEQ
  const unsigned* mpb = pk + ((((size_t)h * 32) * SEQ + (i0 + wave * 16 + quad * 4)) * 16 + lq) * 4;

  for (int jt = 0; jt < SEQ / BN; ++jt) {
    __syncthreads();                                   // B1: prev iter's P/V readers done
    s16x8 kx0 = *(const s16x8*)(kgb + jt * 4096);
    s16x8 kx1 = *(const s16x8*)(kgb + jt * 4096 + 2048);
    s16x8 vx0 = *(const s16x8*)(vgb + jt * 64);
    s16x8 vx1 = *(const s16x8*)(vgb + jt * 64 + 32 * SEQ);
    *(s16x8*)&lds_k[lw]            = kx0;
    *(s16x8*)&lds_k[lw + 32 * KST] = kx1;
    *(s16x8*)&lds_v[lw]            = vx0;
    *(s16x8*)&lds_v[lw + 32 * KST] = vx1;
    __syncthreads();                                   // B2: staging visible

    // S = (Q/8) K^T
    f32x4 sa[4];
    for (int s = 0; s < 4; ++s) sa[s] = (f32x4){0.f, 0.f, 0.f, 0.f};
    for (int k0 = 0; k0 < 2; ++k0)
      for (int s = 0; s < 4; ++s) {
        bf16x8 bk = *(const bf16x8*)&lds_k[(s * 16 + lq) * KST + k0 * 32 + quad * 8];
        sa[s] = __builtin_amdgcn_mfma_f32_16x16x32_bf16(aq[k0], bk, sa[s], 0, 0, 0);
      }
    __syncthreads();                                   // B3: all K reads done; P may overwrite

    // softmax (no max-tracking: exp2 args bounded; uniform scale cancels at normalize)
    const unsigned* mp = mpb + (size_t)jt * (SEQ * 64);
    for (int r = 0; r < 4; ++r) {
      u32x4 u = *(const u32x4*)(mp + r * 64);
      float ps = 0.f;
      for (int s = 0; s < 4; ++s) {
        float mf = __builtin_bit_cast(float, u[s] & 0xffff0000u);  // mask*log2e (bf16)
        float mq = __builtin_bit_cast(float, u[s] << 16);          // mask*pos*log2e (bf16)
        float p  = fast_exp2(fmaf(mf, sa[s][r], mq));
        unsigned pu = __builtin_bit_cast(unsigned, p);
        lds_k[wave * (16 * KST) + (quad * 4 + r) * KST + s * 16 + lq] = (unsigned short)(pu >> 16);
        ps += __builtin_bit_cast(float, pu & 0xffff0000u);         // sum the rounded p
      }
      for (int off = 1; off < 16; off <<= 1) ps += __shfl_xor(ps, off);
      lrun[r] += ps;
    }
    asm volatile("s_waitcnt lgkmcnt(0)" ::: "memory"); // wave-private P visibility

    // O += P V
    for (int k0 = 0; k0 < 2; ++k0) {
      bf16x8 ap = *(const bf16x8*)&lds_k[wave * (16 * KST) + lq * KST + k0 * 32 + quad * 8];
      for (int d = 0; d < 4; ++d) {
        bf16x8 bv = *(const bf16x8*)&lds_v[(d * 16 + lq) * KST + k0 * 32 + quad * 8];
        oacc[d] = __builtin_amdgcn_mfma_f32_16x16x32_bf16(ap, bv, oacc[d], 0, 0, 0);
      }
    }
  }

  for (int r = 0; r < 4; ++r) {
    const float inv = 1.0f / lrun[r];
    float* orow = out + ((size_t)bh * SEQ + i0 + wave * 16 + quad * 4 + r) * HD + lq;
    for (int d = 0; d < 4; ++d) orow[d * 16] = oacc[d][r] * inv;
  }
}

// ---------------- fallback (R1 kernel, used if ws too small) ----------------
__global__ __launch_bounds__(256, 2)
void attn_fused(const float* __restrict__ q, const float* __restrict__ kk,
                const float* __restrict__ vv, const float* __restrict__ pos,
                const float* __restrict__ mask, float* __restrict__ out)
{
  __shared__ short lds_k[BN * KST];
  __shared__ short lds_v[HD * KST];
  __shared__ short lds_p[4][16 * KST];
  const int bh = blockIdx.y, h = bh & (NH - 1);
  const int i0 = blockIdx.x * BM;
  const int tid = threadIdx.x, wave = tid >> 6, lane = tid & 63;
  const int quad = lane >> 4, lq = lane & 15;
  bf16x8 aq[2];
  {
    const float* qp = q + ((size_t)bh * SEQ + i0 + wave * 16 + lq) * HD + quad * 8;
    for (int k0 = 0; k0 < 2; ++k0) {
      f32x4 x = *(const f32x4*)(qp + k0 * 32);
      f32x4 y = *(const f32x4*)(qp + k0 * 32 + 4);
      for (int j = 0; j < 4; ++j) { aq[k0][j] = f2bf(x[j] * INV_T); aq[k0][4 + j] = f2bf(y[j] * INV_T); }
    }
  }
  f32x4 oacc[4];
  for (int d = 0; d < 4; ++d) oacc[d] = (f32x4){0.f, 0.f, 0.f, 0.f};
  float mrun[4] = {-INFINITY, -INFINITY, -INFINITY, -INFINITY};
  float lrun[4] = {0.f, 0.f, 0.f, 0.f};
  const size_t kvbase = (size_t)bh * SEQ * HD;
  for (int jt = 0; jt < SEQ / BN; ++jt) {
    const int j0 = jt * BN;
    __syncthreads();
    for (int e = 0; e < 4; ++e) {
      int idx = e * 256 + tid, j = idx >> 4, d4 = (idx & 15) << 2;
      f32x4 kf = *(const f32x4*)(kk + kvbase + (size_t)(j0 + j) * HD + d4);
      s16x4 ks;
      for (int c = 0; c < 4; ++c) ks[c] = f2bf(kf[c]);
      *(s16x4*)&lds_k[j * KST + d4] = ks;
      f32x4 vf = *(const f32x4*)(vv + kvbase + (size_t)(j0 + j) * HD + d4);
      for (int c = 0; c < 4; ++c) lds_v[(d4 + c) * KST + j] = f2bf(vf[c]);
    }
    __syncthreads();
    float mk[4][4], pz[4][4];
    for (int r = 0; r < 4; ++r) {
      const int i = i0 + wave * 16 + quad * 4 + r;
      const float* mrow = mask + (size_t)i * SEQ + j0 + lq;
      const float* prow = pos + ((size_t)h * SEQ + i) * SEQ + j0 + lq;
      for (int s = 0; s < 4; ++s) { mk[r][s] = mrow[s * 16]; pz[r][s] = prow[s * 16]; }
    }
    f32x4 sa[4];
    for (int s = 0; s < 4; ++s) sa[s] = (f32x4){0.f, 0.f, 0.f, 0.f};
    for (int k0 = 0; k0 < 2; ++k0)
      for (int s = 0; s < 4; ++s) {
        bf16x8 bk = *(const bf16x8*)&lds_k[(s * 16 + lq) * KST + k0 * 32 + quad * 8];
        sa[s] = __builtin_amdgcn_mfma_f32_16x16x32_bf16(aq[k0], bk, sa[s], 0, 0, 0);
      }
    for (int r = 0; r < 4; ++r) {
      float s0 = mk[r][0] * (sa[0][r] + pz[r][0]);
      float s1 = mk[r][1] * (sa[1][r] + pz[r][1]);
      float s2 = mk[r][2] * (sa[2][r] + pz[r][2]);
      float s3 = mk[r][3] * (sa[3][r] + pz[r][3]);
      float rm = fmaxf(fmaxf(s0, s1), fmaxf(s2, s3));
      for (int off = 1; off < 16; off <<= 1) rm = fmaxf(rm, __shfl_xor(rm, off));
      float mn = fmaxf(mrun[r], rm);
      float al = __expf(mrun[r] - mn);
      mrun[r] = mn;
      short p0 = f2bf(__expf(s0 - mn)), p1 = f2bf(__expf(s1 - mn));
      short p2 = f2bf(__expf(s2 - mn)), p3 = f2bf(__expf(s3 - mn));
      float ps = bf2f(p0) + bf2f(p1) + bf2f(p2) + bf2f(p3);
      for (int off = 1; off < 16; off <<= 1) ps += __shfl_xor(ps, off);
      lrun[r] = lrun[r] * al + ps;
      for (int d = 0; d < 4; ++d) oacc[d][r] *= al;
      short* pr = &lds_p[wave][(quad * 4 + r) * KST + lq];
      pr[0] = p0; pr[16] = p1; pr[32] = p2; pr[48] = p3;
    }
    asm volatile("s_waitcnt lgkmcnt(0)" ::: "memory");
    for (int k0 = 0; k0 < 2; ++k0) {
      bf16x8 ap = *(const bf16x8*)&lds_p[wave][lq * KST + k0 * 32 + quad * 8];
      for (int d = 0; d < 4; ++d) {
        bf16x8 bv = *(const bf16x8*)&lds_v[(d * 16 + lq) * KST + k0 * 32 + quad * 8];
        oacc[d] = __builtin_amdgcn_mfma_f32_16x16x32_bf16(ap, bv, oacc[d], 0, 0, 0);
      }
    }
  }
  for (int r = 0; r < 4; ++r) {
    const int i = i0 + wave * 16 + quad * 4 + r;
    const float inv = 1.0f / lrun[r];
    float* orow = out + ((size_t)bh * SEQ + i) * HD + lq;
    for (int d = 0; d < 4; ++d) orow[d * 16] = oacc[d][r] * inv;
  }
}

extern "C" void kernel_launch(void* const* d_in, const int* in_sizes, int n_in,
                              void* d_out, int out_size, void* d_ws, size_t ws_size,
                              hipStream_t stream) {
  const float* q    = (const float*)d_in[0];
  const float* k    = (const float*)d_in[1];
  const float* v    = (const float*)d_in[2];
  const float* pos  = (const float*)d_in[3];
  const float* mask = (const float*)d_in[4];
  float* out = (float*)d_out;

  const size_t kv_elems = (size_t)NB * NH * SEQ * HD;          // 8,388,608
  const size_t kb_bytes = kv_elems * 2;                        // 16 MB
  const size_t pk_dwords = (size_t)NH * SEQ * SEQ;             // 33,554,432
  const size_t need = 2 * kb_bytes + pk_dwords * 4;            // ~168 MB

  if (ws_size >= need) {
    unsigned short* kb = (unsigned short*)d_ws;
    unsigned short* vt = (unsigned short*)((char*)d_ws + kb_bytes);
    unsigned*       pk = (unsigned*)((char*)d_ws + 2 * kb_bytes);
    prep_kv<<<dim3(SEQ / BN, NB * NH), dim3(256), 0, stream>>>(k, v, kb, vt);
    prep_pack<<<dim3((int)(pk_dwords / 4 / 256)), dim3(256), 0, stream>>>(pos, mask, pk);
    attn_main<<<dim3(SEQ / BM, NB * NH), dim3(256), 0, stream>>>(q, kb, vt, pk, out);
  } else {
    attn_fused<<<dim3(SEQ / BM, NB * NH), dim3(256), 0, stream>>>(q, k, v, pos, mask, out);
  }
}